// Round 5
// baseline (184.259 us; speedup 1.0000x reference)
//
#include <hip/hip_runtime.h>

typedef unsigned short u16;
typedef unsigned int u32;

typedef __bf16 bf16x8 __attribute__((ext_vector_type(8)));
typedef float floatx4 __attribute__((ext_vector_type(4)));

// ---- helpers ----------------------------------------------------------------

__device__ __forceinline__ u32 f2bf(float f) {
    // round-to-nearest-even fp32 -> bf16 (bit pattern in low 16)
    u32 u = __builtin_bit_cast(u32, f);
    return (u + 0x7fffu + ((u >> 16) & 1u)) >> 16;
}

__device__ __forceinline__ float quant_w(float x) {
    // WAGE Quantize.W, BITS_W=2: clip to [-0.5,0.5], round to grid step 0.5 (RNE)
    float xc = fminf(fmaxf(x, -0.5f), 0.5f);
    return rintf(xc * 2.0f) * 0.5f;
}

__device__ __forceinline__ void gload_lds16(const u16* g, u16* l) {
    __builtin_amdgcn_global_load_lds(
        (const __attribute__((address_space(1))) void*)g,
        (__attribute__((address_space(3))) void*)l,
        16, 0, 0);
}

// ---- kernel 1: fused A-cast (blocks 0..8191) + W quant+transpose (8192..9215)

__global__ __launch_bounds__(256) void prep_kernel(const float4* __restrict__ Af,
                                                   uint4* __restrict__ Abf,
                                                   const float* __restrict__ W,
                                                   u16* __restrict__ Bt) {
    const int bid = blockIdx.x;
    const int tid = threadIdx.x;
    if (bid < 8192) {
        // cast A fp32 -> bf16, 8 floats / thread
        int t = bid * 256 + tid;
        float4 a = Af[2 * t];
        float4 b = Af[2 * t + 1];
        uint4 o;
        o.x = f2bf(a.x) | (f2bf(a.y) << 16);
        o.y = f2bf(a.z) | (f2bf(a.w) << 16);
        o.z = f2bf(b.x) | (f2bf(b.y) << 16);
        o.w = f2bf(b.z) | (f2bf(b.w) << 16);
        Abf[t] = o;
    } else {
        // quantize + transpose W[k][n] -> Bt[n][k]
        __shared__ u16 tile[32][33];
        const int KN = 1024;
        int b = bid - 8192;          // 0..1023
        int n0 = (b & 31) * 32;
        int k0 = (b >> 5) * 32;
        int tx = tid & 31;           // 0..31
        int ty = tid >> 5;           // 0..7
#pragma unroll
        for (int i = 0; i < 4; i++) {
            int kl = ty + i * 8;
            float x = W[(k0 + kl) * KN + n0 + tx];
            tile[kl][tx] = (u16)f2bf(quant_w(x));
        }
        __syncthreads();
#pragma unroll
        for (int i = 0; i < 4; i++) {
            int nl = ty + i * 8;
            Bt[(n0 + nl) * KN + k0 + tx] = tile[tx][nl];
        }
    }
}

// ---- kernel 2: C[M][N] = A[M][K] * Bt[N][K]^T  (bf16 MFMA, fp32 out) --------
// Round-2 winning shape (BK=64, 32 MFMA per barrier window) with two deltas:
//  * B is NOT staged in LDS: each wave loads its 8 B-fragments global->VGPR,
//    prefetched one tile ahead (compiler drains them with fine-grained vmcnt,
//    not the barrier's vmcnt(0) -- AITER-style pipelining).
//  * A double-buffered (2 x 16 KB, static buffers, x2-unrolled loop) so each
//    barrier's vmcnt(0) drain has a full 32-MFMA compute phase of cover.
// XOR bank-swizzle on A (proven 0-conflict in r2), grid x = M for L2 locality.

struct BF {
    bf16x8 f[8];  // [j*2 + s], j = 16-col tile 0..3, s = k-half 0..1
};

__global__ __launch_bounds__(256) void gemm_bt_kernel(const u16* __restrict__ A,
                                                      const u16* __restrict__ Bt,
                                                      float* __restrict__ C) {
    const int K = 1024;
    const int N = 1024;

    __shared__ alignas(16) u16 As0[128 * 64];  // 16 KB
    __shared__ alignas(16) u16 As1[128 * 64];  // 16 KB

    const int tid = threadIdx.x;
    const int mbase = blockIdx.x * 128;   // x = M: XCD (id%8) gets L2-resident slice
    const int nbase = blockIdx.y * 128;
    const int lane = tid & 63;
    const int wv = tid >> 6;
    const int wm = (wv & 1) * 64;
    const int wn = (wv >> 1) * 64;
    const int frow = lane & 15;           // m (or n) index within 16-tile
    const int fkc = lane >> 4;            // k-chunk (0..3) within a k-half
    const int rsw = frow & 7;             // XOR bank-swizzle key

    // A staging: thread t stages 4 chunks q=0..3; chunk row = q*32 + (t>>3),
    // linear chunk (t&7), global chunk g8 = (t&7) ^ (row&7). LDS dst (q*256+t)*8.
    const int srow = tid >> 3;
    const int g8 = (tid & 7) ^ (srow & 7);
    const u16* Ag[4];
#pragma unroll
    for (int q = 0; q < 4; q++)
        Ag[q] = &A[(size_t)(mbase + q * 32 + srow) * K + g8 * 8];

    // B per-lane base: row nbase+wn+frow, k-chunk fkc. Frag (j,s) at tile kt:
    // Bg + j*16*K + kt + s*32.
    const u16* Bg = &Bt[(size_t)(nbase + wn + frow) * K + fkc * 8];

    floatx4 acc[4][4] = {};

    auto stageA = [&](int kt, u16* __restrict__ dst) {
#pragma unroll
        for (int q = 0; q < 4; q++)
            gload_lds16(Ag[q] + kt, &dst[(q * 256 + tid) * 8]);
    };
    auto loadB = [&](int kt) {
        BF b;
#pragma unroll
        for (int j = 0; j < 4; j++)
#pragma unroll
            for (int s = 0; s < 2; s++)
                b.f[j * 2 + s] = *(const bf16x8*)&Bg[j * 16 * K + kt + s * 32];
        return b;
    };
    auto computeT = [&](const u16* __restrict__ As, const BF& b) {
#pragma unroll
        for (int s = 0; s < 2; s++) {
            bf16x8 af[4];
#pragma unroll
            for (int i = 0; i < 4; i++)
                af[i] = *(const bf16x8*)&As[(wm + i * 16 + frow) * 64 +
                                            (((s * 4 + fkc) ^ rsw) * 8)];
#pragma unroll
            for (int i = 0; i < 4; i++)
#pragma unroll
                for (int j = 0; j < 4; j++)
                    acc[i][j] = __builtin_amdgcn_mfma_f32_16x16x32_bf16(
                        af[i], b.f[j * 2 + s], acc[i][j], 0, 0, 0);
        }
    };

    // 16 tiles of BK=64. Prologue: tile 0.
    stageA(0, As0);
    BF b0 = loadB(0);

#pragma unroll 1
    for (int d = 0; d < 7; ++d) {
        const int kt = d * 128;  // this double-step computes tiles kt, kt+64
        __syncthreads();                 // drains stageA(kt) -- full compute of cover
        stageA(kt + 64, As1);
        BF b1 = loadB(kt + 64);
        computeT(As0, b0);               // tile kt
        __syncthreads();                 // drains stageA(kt+64)
        stageA(kt + 128, As0);
        b0 = loadB(kt + 128);
        computeT(As1, b1);               // tile kt+64
    }
    // tail: tiles 896 (in As0/b0), 960
    __syncthreads();
    stageA(960, As1);
    BF bt = loadB(960);
    computeT(As0, b0);
    __syncthreads();
    computeT(As1, bt);

    // epilogue: C/D layout col = lane&15, row = (lane>>4)*4 + reg
    const int crow = (lane >> 4) * 4;
    const int ccol = lane & 15;
#pragma unroll
    for (int i = 0; i < 4; i++) {
#pragma unroll
        for (int j = 0; j < 4; j++) {
            float* cp = &C[(size_t)(mbase + wm + i * 16 + crow) * N + nbase + wn + j * 16 + ccol];
#pragma unroll
            for (int r = 0; r < 4; r++) cp[r * N] = acc[i][j][r];
        }
    }
}

// ---- launch -----------------------------------------------------------------

extern "C" void kernel_launch(void* const* d_in, const int* in_sizes, int n_in,
                              void* d_out, int out_size, void* d_ws, size_t ws_size,
                              hipStream_t stream) {
    const float* A = (const float*)d_in[0];   // 16384 x 1024
    const float* W = (const float*)d_in[1];   // 1024 x 1024
    float* C = (float*)d_out;                 // 16384 x 1024

    u16* Abf = (u16*)d_ws;                                   // 32 MB
    u16* Btq = (u16*)((char*)d_ws + (size_t)33554432);       // 2 MB

    prep_kernel<<<8192 + 1024, 256, 0, stream>>>((const float4*)A, (uint4*)Abf, W, Btq);
    gemm_bt_kernel<<<dim3(128, 8), 256, 0, stream>>>(Abf, Btq, C);
}

// Round 6
// 158.635 us; speedup vs baseline: 1.1615x; 1.1615x over previous
//
#include <hip/hip_runtime.h>

typedef unsigned short u16;
typedef unsigned int u32;

typedef __bf16 bf16x8 __attribute__((ext_vector_type(8)));
typedef float floatx4 __attribute__((ext_vector_type(4)));

// ---- helpers ----------------------------------------------------------------

__device__ __forceinline__ u32 f2bf(float f) {
    // round-to-nearest-even fp32 -> bf16 (bit pattern in low 16)
    u32 u = __builtin_bit_cast(u32, f);
    return (u + 0x7fffu + ((u >> 16) & 1u)) >> 16;
}

__device__ __forceinline__ float quant_w(float x) {
    // WAGE Quantize.W, BITS_W=2: clip to [-0.5,0.5], round to grid step 0.5 (RNE)
    float xc = fminf(fmaxf(x, -0.5f), 0.5f);
    return rintf(xc * 2.0f) * 0.5f;
}

__device__ __forceinline__ void gload_lds16(const u16* g, u16* l) {
    __builtin_amdgcn_global_load_lds(
        (const __attribute__((address_space(1))) void*)g,
        (__attribute__((address_space(3))) void*)l,
        16, 0, 0);
}

// ---- kernel 1: fused A-cast (blocks 0..8191) + W quant+transpose (8192..9215)

__global__ __launch_bounds__(256) void prep_kernel(const float4* __restrict__ Af,
                                                   uint4* __restrict__ Abf,
                                                   const float* __restrict__ W,
                                                   u16* __restrict__ Bt) {
    const int bid = blockIdx.x;
    const int tid = threadIdx.x;
    if (bid < 8192) {
        // cast A fp32 -> bf16, 8 floats / thread
        int t = bid * 256 + tid;
        float4 a = Af[2 * t];
        float4 b = Af[2 * t + 1];
        uint4 o;
        o.x = f2bf(a.x) | (f2bf(a.y) << 16);
        o.y = f2bf(a.z) | (f2bf(a.w) << 16);
        o.z = f2bf(b.x) | (f2bf(b.y) << 16);
        o.w = f2bf(b.z) | (f2bf(b.w) << 16);
        Abf[t] = o;
    } else {
        // quantize + transpose W[k][n] -> Bt[n][k]
        __shared__ u16 tile[32][33];
        const int KN = 1024;
        int b = bid - 8192;          // 0..1023
        int n0 = (b & 31) * 32;
        int k0 = (b >> 5) * 32;
        int tx = tid & 31;           // 0..31
        int ty = tid >> 5;           // 0..7
#pragma unroll
        for (int i = 0; i < 4; i++) {
            int kl = ty + i * 8;
            float x = W[(k0 + kl) * KN + n0 + tx];
            tile[kl][tx] = (u16)f2bf(quant_w(x));
        }
        __syncthreads();
#pragma unroll
        for (int i = 0; i < 4; i++) {
            int nl = ty + i * 8;
            Bt[(n0 + nl) * KN + k0 + tx] = tile[tx][nl];
        }
    }
}

// ---- kernel 2: C[M][N] = A[M][K] * Bt[N][K]^T  (bf16 MFMA, fp32 out) --------
// Round-2 proven loop structure (BK=64, both operands LDS-staged, plain
// 2-barrier K-loop) scaled to a 256x128 M x N tile with 512 threads (8 waves,
// 4x2): staged bytes per thread drop 8 -> 6 gloads/iter (25% less barrier
// drain), arithmetic intensity per block +33%. Each wave keeps the identical
// 64x64 output, 32 MFMA per barrier window, same XOR swizzle (0-conflict in
// r2), grid x = M-blocks for per-XCD L2 locality.

__global__ __launch_bounds__(512) void gemm_bt_kernel(const u16* __restrict__ A,
                                                      const u16* __restrict__ Bt,
                                                      float* __restrict__ C) {
    const int K = 1024;
    const int N = 1024;

    __shared__ alignas(16) u16 As[256 * 64];  // 32 KB
    __shared__ alignas(16) u16 Bs[128 * 64];  // 16 KB

    const int tid = threadIdx.x;
    const int mbase = blockIdx.x * 256;   // x = M: XCD (id%8) gets L2-resident slice
    const int nbase = blockIdx.y * 128;
    const int lane = tid & 63;
    const int wv = tid >> 6;              // 0..7
    const int wm = (wv & 3) * 64;         // 4 wave-rows
    const int wn = (wv >> 2) * 64;        // 2 wave-cols
    const int frow = lane & 15;           // m (or n) index within 16-tile
    const int fkc = lane >> 4;            // k-chunk (0..3) within a 32-wide k-half
    const int rsw = frow & 7;             // XOR bank-swizzle key

    // staging: chunk c of a tile = 16B; row = c>>3, linear kc = c&7,
    // global kc g8 = (c&7) ^ (row&7)  [bank swizzle, matches reader below].
    // A has 2048 chunks (thread t takes q*512+t, q=0..3); B has 1024 (q=0..1).
    // Since q*64 is a multiple of 8, g8 is the same for all q.
    const int srow = tid >> 3;                       // row within a q-slab
    const int g8 = (tid & 7) ^ (srow & 7);
    const u16* Aga[4];
    const u16* Bga[2];
#pragma unroll
    for (int q = 0; q < 4; q++)
        Aga[q] = &A[(size_t)(mbase + q * 64 + srow) * K + g8 * 8];
#pragma unroll
    for (int q = 0; q < 2; q++)
        Bga[q] = &Bt[(size_t)(nbase + q * 64 + srow) * K + g8 * 8];

    floatx4 acc[4][4] = {};

    for (int kt = 0; kt < K; kt += 64) {
        __syncthreads();  // prior iteration's LDS reads done before overwrite
#pragma unroll
        for (int q = 0; q < 4; q++)
            gload_lds16(Aga[q] + kt, &As[(q * 512 + tid) * 8]);
#pragma unroll
        for (int q = 0; q < 2; q++)
            gload_lds16(Bga[q] + kt, &Bs[(q * 512 + tid) * 8]);
        __syncthreads();  // vmcnt(0) drain + barrier

#pragma unroll
        for (int s = 0; s < 2; s++) {
            bf16x8 af[4], bf[4];
#pragma unroll
            for (int i = 0; i < 4; i++)
                af[i] = *(const bf16x8*)&As[(wm + i * 16 + frow) * 64 +
                                            (((s * 4 + fkc) ^ rsw) * 8)];
#pragma unroll
            for (int j = 0; j < 4; j++)
                bf[j] = *(const bf16x8*)&Bs[(wn + j * 16 + frow) * 64 +
                                            (((s * 4 + fkc) ^ rsw) * 8)];
#pragma unroll
            for (int i = 0; i < 4; i++)
#pragma unroll
                for (int j = 0; j < 4; j++)
                    acc[i][j] = __builtin_amdgcn_mfma_f32_16x16x32_bf16(
                        af[i], bf[j], acc[i][j], 0, 0, 0);
        }
    }

    // epilogue: C/D layout col = lane&15, row = (lane>>4)*4 + reg
    const int crow = (lane >> 4) * 4;
    const int ccol = lane & 15;
#pragma unroll
    for (int i = 0; i < 4; i++) {
#pragma unroll
        for (int j = 0; j < 4; j++) {
            float* cp = &C[(size_t)(mbase + wm + i * 16 + crow) * N + nbase + wn + j * 16 + ccol];
#pragma unroll
            for (int r = 0; r < 4; r++) cp[r * N] = acc[i][j][r];
        }
    }
}

// ---- launch -----------------------------------------------------------------

extern "C" void kernel_launch(void* const* d_in, const int* in_sizes, int n_in,
                              void* d_out, int out_size, void* d_ws, size_t ws_size,
                              hipStream_t stream) {
    const float* A = (const float*)d_in[0];   // 16384 x 1024
    const float* W = (const float*)d_in[1];   // 1024 x 1024
    float* C = (float*)d_out;                 // 16384 x 1024

    u16* Abf = (u16*)d_ws;                                   // 32 MB
    u16* Btq = (u16*)((char*)d_ws + (size_t)33554432);       // 2 MB

    prep_kernel<<<8192 + 1024, 256, 0, stream>>>((const float4*)A, (uint4*)Abf, W, Btq);
    gemm_bt_kernel<<<dim3(64, 8), 512, 0, stream>>>(Abf, Btq, C);
}